// Round 13
// baseline (106.583 us; speedup 1.0000x reference)
//
#include <hip/hip_runtime.h>
#include <math.h>

// Problem constants (match reference)
#define BGRAPH 64
#define N_PER  1024
#define KSEL   512
#define NTOT   65536       // BGRAPH * N_PER
#define EDG    2097152
#define FIN    256
#define FE     16

// d_out flat layout (float32 elements), reference tuple order:
#define OFF_XOUT   0
#define OFF_EI     8388608
#define OFF_EA     12582912
#define OFF_BATCH  46137344
#define OFF_PERM   46170112
#define OFF_SCORE  46202880
#define OFF_EMASK  46268416

// d_ws layout: [0,256KB) node_map (int[65536]); [256KB,768KB) dots (double[65536])
#define WS_DOTS_OFF 65536   // in ints

#define GATHER_BLOCKS 8192   // (BGRAPH*KSEL)/4 rows, 4 rows/block
#define EDGE_BLOCKS   2048   // EDG/1024 edges, 1024 edges/block

// ---------------------------------------------------------------------------
// Kernel 1 (R13: 8-row waves): z = dot(x,W)+b in f64 rank key; value via
// monotone-equivalent f32 tanhf. R12 proved this kernel is ISSUE-bound, not
// BW-bound (4-row waves: -5 us, prediction matched). 8 rows/wave: 8 lanes
// per row, 8 float4/lane (16 loads in flight), 3 shuffle rounds per 8 rows.
// f64 accumulation order per row unchanged in spirit (tree reshape re-rolls
// only ~1e-13 sum diffs; validated safe in R12).
__global__ __launch_bounds__(256) void score_kernel(
    const float* __restrict__ x, const float* __restrict__ W,
    const float* __restrict__ bptr, float* __restrict__ score_out,
    double* __restrict__ dot_out) {
  int wave = threadIdx.x >> 6;
  int lane = threadIdx.x & 63;
  int sub  = lane >> 3;            // which of the wave's 8 rows
  int l8   = lane & 7;             // lane within the 8-lane row group
  int row  = (blockIdx.x * 4 + wave) * 8 + sub;
  const float4* xr = reinterpret_cast<const float4*>(x + (size_t)row * FIN);
  const float4* wr = reinterpret_cast<const float4*>(W);   // 1 KB, L1-hot
  double p = 0.0;
#pragma unroll
  for (int q = 0; q < 8; ++q) {
    float4 xv = xr[q * 8 + l8];
    float4 wv = wr[q * 8 + l8];
    p += (double)xv.x * (double)wv.x + (double)xv.y * (double)wv.y +
         (double)xv.z * (double)wv.z + (double)xv.w * (double)wv.w;
  }
#pragma unroll
  for (int off = 4; off >= 1; off >>= 1) p += __shfl_xor(p, off, 64);
  if (l8 == 0) {
    double z = p + (double)bptr[0];
    dot_out[row]   = z;
    score_out[row] = tanhf((float)z);   // MULTIPLIER == 1.0
  }
}

// ---------------------------------------------------------------------------
// Kernel 2 (R13: 2 elems/thread, 512 threads): same bitonic network on 1024
// (f64 dot, idx) pairs — desc key, ties idx-asc — repartitioned so thread t
// owns positions 2t, 2t+1:
//   j==1  : in-register compare-exchange (10 stages, zero barriers)
//   j<=64 : wave-internal __shfl_xor of both elements (lane xor j/2 <= 32)
//   j>=128: LDS, 2 barriers (6 phases -> 12 barriers x 8 waves, was 20 x 16)
// Semantics identical to the verified 1024-thread version (same compares,
// same order); only the thread partitioning changed.
__global__ __launch_bounds__(512) void topk_kernel(
    const double* __restrict__ dots, float* __restrict__ perm_out,
    float* __restrict__ batch_out, int* __restrict__ node_map) {
  __shared__ double sk[N_PER];
  __shared__ int    si[N_PER];
  int b = blockIdx.x;
  int t = threadIdx.x;
  int base = b * N_PER;
  int i0 = 2 * t, i1 = 2 * t + 1;
  double k0 = dots[base + i0], k1 = dots[base + i1];
  int id0 = i0, id1 = i1;
  node_map[base + i0] = -1;
  node_map[base + i1] = -1;
  for (int k = 2; k <= N_PER; k <<= 1) {
    for (int j = k >> 1; j > 0; j >>= 1) {
      if (j == 1) {
        // partner is the in-thread sibling; i0 is always the lower index
        bool dirUp = ((i0 & k) == 0);
        bool own_prec = (k0 > k1) || (k0 == k1 && id0 < id1);
        if (own_prec != dirUp) {
          double tk = k0; k0 = k1; k1 = tk;
          int    ti = id0; id0 = id1; id1 = ti;
        }
      } else {
        // both elements pair with the SAME partner thread t ^ (j>>1);
        // lower/dir identical for both slots (j,k >= 2).
        bool lower = ((i0 & j) == 0);
        bool dirUp = ((i0 & k) == 0);
        bool want  = (lower == dirUp);
        double ok0, ok1; int oid0, oid1;
        if (j <= 64) {
          int lx = j >> 1;              // <= 32: wave-internal
          ok0 = __shfl_xor(k0, lx, 64);  oid0 = __shfl_xor(id0, lx, 64);
          ok1 = __shfl_xor(k1, lx, 64);  oid1 = __shfl_xor(id1, lx, 64);
        } else {
          sk[i0] = k0; si[i0] = id0;
          sk[i1] = k1; si[i1] = id1;
          __syncthreads();
          ok0 = sk[i0 ^ j]; oid0 = si[i0 ^ j];
          ok1 = sk[i1 ^ j]; oid1 = si[i1 ^ j];
          __syncthreads();
        }
        bool prec0 = (k0 > ok0) || (k0 == ok0 && id0 < oid0);
        if (prec0 != want) { k0 = ok0; id0 = oid0; }
        bool prec1 = (k1 > ok1) || (k1 == ok1 && id1 < oid1);
        if (prec1 != want) { k1 = ok1; id1 = oid1; }
      }
    }
  }
  if (t < KSEL / 2) {
    int g0 = base + id0, g1 = base + id1;
    int gid0 = b * KSEL + i0, gid1 = b * KSEL + i1;
    perm_out[gid0]  = (float)g0;
    perm_out[gid1]  = (float)g1;
    batch_out[gid0] = (float)b;
    batch_out[gid1] = (float)b;
    node_map[g0]    = gid0;
    node_map[g1]    = gid1;
  }
}

// ---------------------------------------------------------------------------
// Kernel 3 (FROZEN from R11): gather + edge fused by block range.
// Gather blocks first (x still L3-hot from score); edge blocks ramp while
// gather drains. Bodies identical to the verified R10 code.
__global__ __launch_bounds__(256) void tail_kernel(
    const float* __restrict__ x, const float* __restrict__ perm_f,
    const float* __restrict__ score, float* __restrict__ xout,
    const int* __restrict__ ei, const int* __restrict__ node_map,
    const float* __restrict__ ea, float* __restrict__ ei_out,
    float* __restrict__ emask_out, float* __restrict__ ea_out) {
  __shared__ float smask[1024];
  int t = threadIdx.x;

  if (blockIdx.x < GATHER_BLOCKS) {
    // ---- gather: 4 rows of x_out ----
    int wave = t >> 6;
    int lane = t & 63;
    int r = blockIdx.x * 4 + wave;
    int g = (int)perm_f[r];           // exact (<= 65535)
    float s = score[g];
    float4 v = reinterpret_cast<const float4*>(x + (size_t)g * FIN)[lane];
    float4 o;
    o.x = v.x * s; o.y = v.y * s; o.z = v.z * s; o.w = v.w * s;
    reinterpret_cast<float4*>(xout + (size_t)r * FIN)[lane] = o;
    return;
  }

  // ---- edge: 1024 edges (mask/remap + attr copy) ----
  int bid = blockIdx.x - GATHER_BLOCKS;
  int e0 = bid * 1024;                 // edges [e0, e0+1024)
  int ft = bid * 256 + t;              // int4/float4 unit index for phase 1

  int4 r4 = reinterpret_cast<const int4*>(ei)[ft];
  int4 c4 = reinterpret_cast<const int4*>(ei + EDG)[ft];
  int nr0 = node_map[r4.x], nr1 = node_map[r4.y];
  int nr2 = node_map[r4.z], nr3 = node_map[r4.w];
  int nc0 = node_map[c4.x], nc1 = node_map[c4.y];
  int nc2 = node_map[c4.z], nc3 = node_map[c4.w];
  bool m0 = (nr0 >= 0) && (nc0 >= 0);
  bool m1 = (nr1 >= 0) && (nc1 >= 0);
  bool m2 = (nr2 >= 0) && (nc2 >= 0);
  bool m3 = (nr3 >= 0) && (nc3 >= 0);
  float4 ro = make_float4(m0 ? (float)nr0 : -1.0f, m1 ? (float)nr1 : -1.0f,
                          m2 ? (float)nr2 : -1.0f, m3 ? (float)nr3 : -1.0f);
  float4 co = make_float4(m0 ? (float)nc0 : -1.0f, m1 ? (float)nc1 : -1.0f,
                          m2 ? (float)nc2 : -1.0f, m3 ? (float)nc3 : -1.0f);
  float4 mo = make_float4(m0 ? 1.0f : 0.0f, m1 ? 1.0f : 0.0f,
                          m2 ? 1.0f : 0.0f, m3 ? 1.0f : 0.0f);
  reinterpret_cast<float4*>(ei_out)[ft]       = ro;
  reinterpret_cast<float4*>(ei_out + EDG)[ft] = co;
  reinterpret_cast<float4*>(emask_out)[ft]    = mo;
  reinterpret_cast<float4*>(smask)[t]         = mo;
  __syncthreads();

  const float4* ea4 = reinterpret_cast<const float4*>(ea) + (size_t)e0 * 4;
  float4*      out4 = reinterpret_cast<float4*>(ea_out)   + (size_t)e0 * 4;
#pragma unroll
  for (int q = 0; q < 16; ++q) {
    int fi = q * 256 + t;                 // local float4 index in [0,4096)
    float mm = smask[fi >> 2];
    float4 v = make_float4(0.f, 0.f, 0.f, 0.f);
    if (mm != 0.0f) v = ea4[fi];
    out4[fi] = v;
  }
}

// ---------------------------------------------------------------------------
extern "C" void kernel_launch(void* const* d_in, const int* in_sizes, int n_in,
                              void* d_out, int out_size, void* d_ws, size_t ws_size,
                              hipStream_t stream) {
  const float* x  = (const float*)d_in[0];
  const int*   ei = (const int*)d_in[1];
  const float* ea = (const float*)d_in[2];
  // d_in[3] = batch (unused: graphs contiguous & equal size)
  const float* W  = (const float*)d_in[4];
  const float* bb = (const float*)d_in[5];

  float* out       = (float*)d_out;
  float* xout      = out + OFF_XOUT;
  float* ei_out    = out + OFF_EI;
  float* ea_out    = out + OFF_EA;
  float* batch_out = out + OFF_BATCH;
  float* perm_out  = out + OFF_PERM;
  float* score_out = out + OFF_SCORE;
  float* emask_out = out + OFF_EMASK;

  int*    node_map = (int*)d_ws;                          // 256 KB
  double* dots     = (double*)((int*)d_ws + WS_DOTS_OFF); // 512 KB @ +256KB

  score_kernel <<<NTOT / 32, 256, 0, stream>>>(x, W, bb, score_out, dots);
  topk_kernel  <<<BGRAPH, 512, 0, stream>>>(dots, perm_out, batch_out, node_map);
  tail_kernel  <<<GATHER_BLOCKS + EDGE_BLOCKS, 256, 0, stream>>>(
      x, perm_out, score_out, xout, ei, node_map, ea, ei_out, emask_out, ea_out);
}

// Round 14
// 102.927 us; speedup vs baseline: 1.0355x; 1.0355x over previous
//
#include <hip/hip_runtime.h>
#include <math.h>

// ============================================================================
// R14 = exact revert to R12 (verified best: 102.9 us, absmax 128).
// R13's two refinements (8-row score wave, 2-elem topk) both regressed;
// this restores the verified-fastest configuration.
// ============================================================================

// Problem constants (match reference)
#define BGRAPH 64
#define N_PER  1024
#define KSEL   512
#define NTOT   65536       // BGRAPH * N_PER
#define EDG    2097152
#define FIN    256
#define FE     16

// d_out flat layout (float32 elements), reference tuple order:
#define OFF_XOUT   0
#define OFF_EI     8388608
#define OFF_EA     12582912
#define OFF_BATCH  46137344
#define OFF_PERM   46170112
#define OFF_SCORE  46202880
#define OFF_EMASK  46268416

// d_ws layout: [0,256KB) node_map (int[65536]); [256KB,768KB) dots (double[65536])
#define WS_DOTS_OFF 65536   // in ints

#define GATHER_BLOCKS 8192   // (BGRAPH*KSEL)/4 rows, 4 rows/block
#define EDGE_BLOCKS   2048   // EDG/1024 edges, 1024 edges/block

// ---------------------------------------------------------------------------
// Kernel 1 (R12 quad-row, VERIFIED -5us vs wave-per-row): z = dot(x,W)+b in
// f64 rank key; value via monotone-equivalent f32 tanhf. Each wave handles
// 4 rows (16 lanes/row, 4 float4 loads/lane): ~3x fewer issue slots per row.
__global__ __launch_bounds__(256) void score_kernel(
    const float* __restrict__ x, const float* __restrict__ W,
    const float* __restrict__ bptr, float* __restrict__ score_out,
    double* __restrict__ dot_out) {
  int wave = threadIdx.x >> 6;
  int lane = threadIdx.x & 63;
  int sub  = lane >> 4;            // which of the wave's 4 rows
  int l16  = lane & 15;            // lane within the 16-lane row group
  int row  = (blockIdx.x * 4 + wave) * 4 + sub;
  const float4* xr = reinterpret_cast<const float4*>(x + (size_t)row * FIN);
  const float4* wr = reinterpret_cast<const float4*>(W);   // 1 KB, L1-hot
  double p = 0.0;
#pragma unroll
  for (int q = 0; q < 4; ++q) {
    float4 xv = xr[q * 16 + l16];
    float4 wv = wr[q * 16 + l16];
    p += (double)xv.x * (double)wv.x + (double)xv.y * (double)wv.y +
         (double)xv.z * (double)wv.z + (double)xv.w * (double)wv.w;
  }
#pragma unroll
  for (int off = 8; off >= 1; off >>= 1) p += __shfl_xor(p, off, 64);
  if (l16 == 0) {
    double z = p + (double)bptr[0];
    dot_out[row]   = z;
    score_out[row] = tanhf((float)z);   // MULTIPLIER == 1.0
  }
}

// ---------------------------------------------------------------------------
// Kernel 2 (R12 1024-thread hybrid, VERIFIED): per-graph bitonic sort of
// (f64 dot, idx). j<=32 via __shfl_xor (no barrier), j>=64 via LDS.
// Desc key, ties idx-asc (lax.top_k stable).
__global__ __launch_bounds__(1024) void topk_kernel(
    const double* __restrict__ dots, float* __restrict__ perm_out,
    float* __restrict__ batch_out, int* __restrict__ node_map) {
  __shared__ double sk[N_PER];
  __shared__ int    si[N_PER];
  int b = blockIdx.x;
  int t = threadIdx.x;
  int base = b * N_PER;
  double key = dots[base + t];
  int    idx = t;
  node_map[base + t] = -1;   // block owns exactly its graph's slice
  for (int k = 2; k <= N_PER; k <<= 1) {
    for (int j = k >> 1; j > 0; j >>= 1) {
      bool lower = (t & j) == 0;
      bool dirUp = (t & k) == 0;
      double okey; int oidx;
      if (j >= 64) {
        sk[t] = key; si[t] = idx;
        __syncthreads();
        okey = sk[t ^ j]; oidx = si[t ^ j];
        __syncthreads();
      } else {
        okey = __shfl_xor(key, j, 64);
        oidx = __shfl_xor(idx, j, 64);
      }
      bool own_prec = (key > okey) || (key == okey && idx < oidx);
      bool want_prec = (lower == dirUp);
      if (own_prec != want_prec) { key = okey; idx = oidx; }
    }
  }
  if (t < KSEL) {
    int g   = base + idx;          // global node id
    int gid = b * KSEL + t;        // remapped id (rank order)
    perm_out[gid]  = (float)g;
    batch_out[gid] = (float)b;
    node_map[g]    = gid;
  }
}

// ---------------------------------------------------------------------------
// Kernel 3 (R11 fused tail, VERIFIED): gather + edge by block range.
// Gather blocks first (x still L3-hot from score); edge blocks ramp while
// gather drains.
__global__ __launch_bounds__(256) void tail_kernel(
    const float* __restrict__ x, const float* __restrict__ perm_f,
    const float* __restrict__ score, float* __restrict__ xout,
    const int* __restrict__ ei, const int* __restrict__ node_map,
    const float* __restrict__ ea, float* __restrict__ ei_out,
    float* __restrict__ emask_out, float* __restrict__ ea_out) {
  __shared__ float smask[1024];
  int t = threadIdx.x;

  if (blockIdx.x < GATHER_BLOCKS) {
    // ---- gather: 4 rows of x_out ----
    int wave = t >> 6;
    int lane = t & 63;
    int r = blockIdx.x * 4 + wave;
    int g = (int)perm_f[r];           // exact (<= 65535)
    float s = score[g];
    float4 v = reinterpret_cast<const float4*>(x + (size_t)g * FIN)[lane];
    float4 o;
    o.x = v.x * s; o.y = v.y * s; o.z = v.z * s; o.w = v.w * s;
    reinterpret_cast<float4*>(xout + (size_t)r * FIN)[lane] = o;
    return;
  }

  // ---- edge: 1024 edges (mask/remap + attr copy) ----
  int bid = blockIdx.x - GATHER_BLOCKS;
  int e0 = bid * 1024;                 // edges [e0, e0+1024)
  int ft = bid * 256 + t;              // int4/float4 unit index for phase 1

  int4 r4 = reinterpret_cast<const int4*>(ei)[ft];
  int4 c4 = reinterpret_cast<const int4*>(ei + EDG)[ft];
  int nr0 = node_map[r4.x], nr1 = node_map[r4.y];
  int nr2 = node_map[r4.z], nr3 = node_map[r4.w];
  int nc0 = node_map[c4.x], nc1 = node_map[c4.y];
  int nc2 = node_map[c4.z], nc3 = node_map[c4.w];
  bool m0 = (nr0 >= 0) && (nc0 >= 0);
  bool m1 = (nr1 >= 0) && (nc1 >= 0);
  bool m2 = (nr2 >= 0) && (nc2 >= 0);
  bool m3 = (nr3 >= 0) && (nc3 >= 0);
  float4 ro = make_float4(m0 ? (float)nr0 : -1.0f, m1 ? (float)nr1 : -1.0f,
                          m2 ? (float)nr2 : -1.0f, m3 ? (float)nr3 : -1.0f);
  float4 co = make_float4(m0 ? (float)nc0 : -1.0f, m1 ? (float)nc1 : -1.0f,
                          m2 ? (float)nc2 : -1.0f, m3 ? (float)nc3 : -1.0f);
  float4 mo = make_float4(m0 ? 1.0f : 0.0f, m1 ? 1.0f : 0.0f,
                          m2 ? 1.0f : 0.0f, m3 ? 1.0f : 0.0f);
  reinterpret_cast<float4*>(ei_out)[ft]       = ro;
  reinterpret_cast<float4*>(ei_out + EDG)[ft] = co;
  reinterpret_cast<float4*>(emask_out)[ft]    = mo;
  reinterpret_cast<float4*>(smask)[t]         = mo;
  __syncthreads();

  const float4* ea4 = reinterpret_cast<const float4*>(ea) + (size_t)e0 * 4;
  float4*      out4 = reinterpret_cast<float4*>(ea_out)   + (size_t)e0 * 4;
#pragma unroll
  for (int q = 0; q < 16; ++q) {
    int fi = q * 256 + t;                 // local float4 index in [0,4096)
    float mm = smask[fi >> 2];
    float4 v = make_float4(0.f, 0.f, 0.f, 0.f);
    if (mm != 0.0f) v = ea4[fi];
    out4[fi] = v;
  }
}

// ---------------------------------------------------------------------------
extern "C" void kernel_launch(void* const* d_in, const int* in_sizes, int n_in,
                              void* d_out, int out_size, void* d_ws, size_t ws_size,
                              hipStream_t stream) {
  const float* x  = (const float*)d_in[0];
  const int*   ei = (const int*)d_in[1];
  const float* ea = (const float*)d_in[2];
  // d_in[3] = batch (unused: graphs contiguous & equal size)
  const float* W  = (const float*)d_in[4];
  const float* bb = (const float*)d_in[5];

  float* out       = (float*)d_out;
  float* xout      = out + OFF_XOUT;
  float* ei_out    = out + OFF_EI;
  float* ea_out    = out + OFF_EA;
  float* batch_out = out + OFF_BATCH;
  float* perm_out  = out + OFF_PERM;
  float* score_out = out + OFF_SCORE;
  float* emask_out = out + OFF_EMASK;

  int*    node_map = (int*)d_ws;                          // 256 KB
  double* dots     = (double*)((int*)d_ws + WS_DOTS_OFF); // 512 KB @ +256KB

  score_kernel <<<NTOT / 16, 256, 0, stream>>>(x, W, bb, score_out, dots);
  topk_kernel  <<<BGRAPH, 1024, 0, stream>>>(dots, perm_out, batch_out, node_map);
  tail_kernel  <<<GATHER_BLOCKS + EDGE_BLOCKS, 256, 0, stream>>>(
      x, perm_out, score_out, xout, ei, node_map, ea, ei_out, emask_out, ea_out);
}